// Round 6
// baseline (362.565 us; speedup 1.0000x reference)
//
#include <hip/hip_runtime.h>

#define N_TOK 16384
#define DIM 2048
#define KCLS 64
#define JRANGES 32
#define RANGE 512   // N_TOK / JRANGES
#define GRP 8       // classes per block group
#define NGRP 8      // KCLS / GRP
#define CH 8        // tokens per staged chunk
#define NCH (RANGE / CH)
#define EPS 1e-8f

// Canonical GCN wave64 sum-reduction on the VALU pipe (DPP); total in lane 63.
__device__ __forceinline__ float dpp_sum64(float x) {
    x += __int_as_float(__builtin_amdgcn_update_dpp(0, __float_as_int(x), 0x111, 0xf, 0xf, true));
    x += __int_as_float(__builtin_amdgcn_update_dpp(0, __float_as_int(x), 0x112, 0xf, 0xf, true));
    x += __int_as_float(__builtin_amdgcn_update_dpp(0, __float_as_int(x), 0x114, 0xf, 0xf, true));
    x += __int_as_float(__builtin_amdgcn_update_dpp(0, __float_as_int(x), 0x118, 0xf, 0xf, true));
    x += __int_as_float(__builtin_amdgcn_update_dpp(0, __float_as_int(x), 0x142, 0xf, 0xf, true));
    x += __int_as_float(__builtin_amdgcn_update_dpp(0, __float_as_int(x), 0x143, 0xf, 0xf, true));
    return x;  // valid in lane 63 only
}

__device__ __forceinline__ float bcast63(float x) {
    return __int_as_float(__builtin_amdgcn_readlane(__float_as_int(x), 63));
}

// ---------------------------------------------------------------------------
// Kernel 0: sniff labels dtype (int64 vs int32) per block, normalize to int32.
__global__ __launch_bounds__(256) void fix_labels_kernel(
    const int* __restrict__ raw, int* __restrict__ lab) {
    __shared__ int not64;
    int t = threadIdx.x, b = blockIdx.x;
    if (t == 0) not64 = 0;
    __syncthreads();
    int n0 = b * 256 + t;
    int lo = raw[2 * n0], hi = raw[2 * n0 + 1];
    if (hi != 0 || lo < 0 || lo >= KCLS) atomicOr(&not64, 1);
    __syncthreads();
    lab[n0] = not64 ? raw[n0] : raw[2 * n0];
}

// ---------------------------------------------------------------------------
// Kernel 1: per-(range, class) partial sum of class-k token vectors.
__global__ __launch_bounds__(256) void partials_kernel(
    const float* __restrict__ x, const int* __restrict__ lab,
    float* __restrict__ spart, int* __restrict__ cnt_range) {
    int bid = blockIdx.x;
    int k = bid & 63, j = bid >> 6;
    int t = threadIdx.x;
    __shared__ int ll[RANGE];
    __shared__ short ml[RANGE];
    __shared__ int nm_s;
    for (int i = t; i < RANGE; i += 256) ll[i] = lab[j * RANGE + i];
    __syncthreads();
    if (t == 0) {
        int nm = 0;
        for (int i = 0; i < RANGE; i++)
            if (ll[i] == k) ml[nm++] = (short)i;
        nm_s = nm;
        cnt_range[j * KCLS + k] = nm;
    }
    __syncthreads();
    int nm = nm_s;
    float4 a = {0, 0, 0, 0}, b4 = {0, 0, 0, 0};
    for (int m = 0; m < nm; m++) {
        const float* r = x + (size_t)(j * RANGE + (int)ml[m]) * DIM;
        float4 xa = *(const float4*)(r + t * 4);
        float4 xb = *(const float4*)(r + 1024 + t * 4);
        a.x += xa.x; a.y += xa.y; a.z += xa.z; a.w += xa.w;
        b4.x += xb.x; b4.y += xb.y; b4.z += xb.z; b4.w += xb.w;
    }
    float* dst = spart + ((size_t)j * KCLS + k) * DIM;
    *(float4*)(dst + t * 4) = a;
    *(float4*)(dst + 1024 + t * 4) = b4;
}

// ---------------------------------------------------------------------------
// Kernel 2: in-place exclusive scan over ranges -> boundary snapshots.
__global__ __launch_bounds__(256) void scan_kernel(
    const float* __restrict__ avgs, float* __restrict__ spart,
    const int* __restrict__ cnt_range, int* __restrict__ cnt_before) {
    int t = blockIdx.x * 256 + threadIdx.x;  // 32768 threads
    int k = t >> 9;
    int d4 = t & 511;
    int d = d4 * 4;
    float4 run = {0, 0, 0, 0};
    int cb = 0;
    float4 init = *(const float4*)(avgs + (size_t)k * DIM + d);
    for (int j = 0; j < JRANGES; j++) {
        size_t idx = ((size_t)j * KCLS + k) * DIM + d;
        float4 part = *(const float4*)(spart + idx);
        float4 w = (cb == 0) ? init : run;
        *(float4*)(spart + idx) = w;
        if (d4 == 0) cnt_before[j * KCLS + k] = cb;
        run.x += part.x; run.y += part.y; run.z += part.z; run.w += part.w;
        cb += cnt_range[j * KCLS + k];
    }
}

// ---------------------------------------------------------------------------
// Kernel 3 (v5): barrier-light VALU main kernel, 16 waves.
// Wave w: proto pair p = w&3 (classes c0=g8+2p, c1=c0+1) held in 64 true
// VGPRs; copy q = w>>2 outputs tokens {2q, 2q+1} of each 8-token chunk and
// replays every event of its pair (identical update sequence in all 4 copies
// -> no cross-wave sync ever). Token norm computed in-wave (3rd fma chain).
// Double-buffered global_load_lds staging; ONE __syncthreads per chunk.
// bid = g*32 + j -> bid%8 == j%8: same-range blocks share an XCD L2.
__global__ __launch_bounds__(1024) void main_kernel(
    const float* __restrict__ x, const int* __restrict__ lab,
    const float* __restrict__ snap, const int* __restrict__ cnt_before,
    float* __restrict__ out) {
    __shared__ float TB[2][CH][DIM];       // 128 KB staged token chunks
    __shared__ unsigned char lbl[RANGE];

    int bid = blockIdx.x;
    int g = bid >> 5, j = bid & 31;
    int g8 = g * GRP;
    int start = j * RANGE;
    int t = threadIdx.x;
    int lane = t & 63, w = t >> 6;     // wave 0..15
    int p = w & 3;                     // proto pair 0..3
    int q = w >> 2;                    // copy / token subset 0..3
    int c0 = g8 + 2 * p, c1 = c0 + 1;

    if (t < RANGE) lbl[t] = (unsigned char)lab[start + t];

    // 2 register-resident prototypes
    float4 P0[8], P1[8];
    {
        const float* s0 = snap + (size_t)(j * KCLS + c0) * DIM;
        const float* s1 = snap + (size_t)(j * KCLS + c1) * DIM;
#pragma unroll
        for (int it = 0; it < 8; it++) {
            P0[it] = *(const float4*)(s0 + it * 256 + lane * 4);
            P1[it] = *(const float4*)(s1 + it * 256 + lane * 4);
        }
    }
    float n20, n21, in0, in1;
    {
        float a = 0.f, bq = 0.f;
#pragma unroll
        for (int it = 0; it < 8; it++) {
            float4 u = P0[it], v = P1[it];
            a = fmaf(u.x, u.x, a); a = fmaf(u.y, u.y, a);
            a = fmaf(u.z, u.z, a); a = fmaf(u.w, u.w, a);
            bq = fmaf(v.x, v.x, bq); bq = fmaf(v.y, v.y, bq);
            bq = fmaf(v.z, v.z, bq); bq = fmaf(v.w, v.w, bq);
        }
        n20 = bcast63(dpp_sum64(a));
        n21 = bcast63(dpp_sum64(bq));
        in0 = 1.0f / fmaxf(sqrtf(n20), EPS);
        in1 = 1.0f / fmaxf(sqrtf(n21), EPS);
    }
    unsigned vm = 0;
    if (cnt_before[j * KCLS + c0] == 0) vm |= 1u;
    if (cnt_before[j * KCLS + c1] == 0) vm |= 2u;

    // stage chunk 0: wave w stages half (w&1) of token (w>>1)
    {
        int tk = w >> 1, h = w & 1;
        const float* src = x + (size_t)(start + tk) * DIM + h * 1024;
#pragma unroll
        for (int it = 0; it < 4; it++)
            __builtin_amdgcn_global_load_lds(
                (__attribute__((address_space(1))) void*)(src + it * 256 + lane * 4),
                (__attribute__((address_space(3))) void*)&TB[0][tk][h * 1024 + it * 256],
                16, 0, 0);
    }
    __syncthreads();  // lbl staged + chunk 0 resident

    int b = 0;
    for (int chk = 0; chk < NCH; chk++) {
        if (chk + 1 < NCH) {  // prefetch next chunk into other buffer
            int tk = w >> 1, h = w & 1;
            const float* src = x + (size_t)(start + (chk + 1) * CH + tk) * DIM + h * 1024;
#pragma unroll
            for (int it = 0; it < 4; it++)
                __builtin_amdgcn_global_load_lds(
                    (__attribute__((address_space(1))) void*)(src + it * 256 + lane * 4),
                    (__attribute__((address_space(3))) void*)&TB[1 - b][tk][h * 1024 + it * 256],
                    16, 0, 0);
        }
        int base = chk * CH;
#pragma unroll 1
        for (int tok = 0; tok < CH; tok++) {
            int lb = lbl[base + tok];
            bool ev = (lb == c0) | (lb == c1);
            bool asg = ((tok >> 1) == q);
            if (!(ev | asg)) continue;

            float a0 = 0.f, a1 = 0.f, nn = 0.f;
#pragma unroll
            for (int it = 0; it < 8; it++) {
                float4 xv = *(const float4*)&TB[b][tok][it * 256 + lane * 4];
                a0 = fmaf(xv.x, P0[it].x, a0); a0 = fmaf(xv.y, P0[it].y, a0);
                a0 = fmaf(xv.z, P0[it].z, a0); a0 = fmaf(xv.w, P0[it].w, a0);
                a1 = fmaf(xv.x, P1[it].x, a1); a1 = fmaf(xv.y, P1[it].y, a1);
                a1 = fmaf(xv.z, P1[it].z, a1); a1 = fmaf(xv.w, P1[it].w, a1);
                nn = fmaf(xv.x, xv.x, nn); nn = fmaf(xv.y, xv.y, nn);
                nn = fmaf(xv.z, xv.z, nn); nn = fmaf(xv.w, xv.w, nn);
            }
            float r0 = dpp_sum64(a0);
            float r1 = dpp_sum64(a1);
            float rn = dpp_sum64(nn);

            if (asg && lane == 63) {
                float iv = 1.0f / fmaxf(sqrtf(rn), EPS);
                float2 o = make_float2(r0 * in0 * iv, r1 * in1 * iv);
                *(float2*)&out[(size_t)(start + base + tok) * KCLS + c0] = o;
            }
            if (ev) {
                bool e0 = (lb == c0);
                float rd = bcast63(e0 ? r0 : r1);
                float vn2 = bcast63(rn);
                if (e0) {
                    if (vm & 1u) {  // first-ever token of this class
#pragma unroll
                        for (int it = 0; it < 8; it++)
                            P0[it] = *(const float4*)&TB[b][tok][it * 256 + lane * 4];
                        n20 = vn2;
                    } else {
#pragma unroll
                        for (int it = 0; it < 8; it++) {
                            float4 xv = *(const float4*)&TB[b][tok][it * 256 + lane * 4];
                            P0[it].x += xv.x; P0[it].y += xv.y;
                            P0[it].z += xv.z; P0[it].w += xv.w;
                        }
                        n20 += 2.0f * rd + vn2;
                    }
                    vm &= ~1u;
                    in0 = 1.0f / fmaxf(sqrtf(n20), EPS);
                } else {
                    if (vm & 2u) {
#pragma unroll
                        for (int it = 0; it < 8; it++)
                            P1[it] = *(const float4*)&TB[b][tok][it * 256 + lane * 4];
                        n21 = vn2;
                    } else {
#pragma unroll
                        for (int it = 0; it < 8; it++) {
                            float4 xv = *(const float4*)&TB[b][tok][it * 256 + lane * 4];
                            P1[it].x += xv.x; P1[it].y += xv.y;
                            P1[it].z += xv.z; P1[it].w += xv.w;
                        }
                        n21 += 2.0f * rd + vn2;
                    }
                    vm &= ~2u;
                    in1 = 1.0f / fmaxf(sqrtf(n21), EPS);
                }
            }
        }
        __syncthreads();  // all reads of TB[b] done + next chunk fully staged
        b ^= 1;
    }
}

// ---------------------------------------------------------------------------
extern "C" void kernel_launch(void* const* d_in, const int* in_sizes, int n_in,
                              void* d_out, int out_size, void* d_ws, size_t ws_size,
                              hipStream_t stream) {
    const float* inputs = (const float*)d_in[0];
    const float* class_avgs = (const float*)d_in[1];
    const int* labels_raw = (const int*)d_in[2];
    float* out = (float*)d_out;
    char* ws = (char*)d_ws;

    size_t off = 0;
    int* lab = (int*)(ws + off);        off += (size_t)N_TOK * 4;
    int* cnt_range = (int*)(ws + off);  off += (size_t)JRANGES * KCLS * 4;
    int* cnt_before = (int*)(ws + off); off += (size_t)JRANGES * KCLS * 4;
    off = (off + 255) & ~(size_t)255;
    float* spart = (float*)(ws + off);  // JRANGES*KCLS*DIM floats = 16 MB

    fix_labels_kernel<<<N_TOK / 256, 256, 0, stream>>>(labels_raw, lab);
    partials_kernel<<<JRANGES * KCLS, 256, 0, stream>>>(inputs, lab, spart, cnt_range);
    scan_kernel<<<(KCLS * (DIM / 4)) / 256, 256, 0, stream>>>(class_avgs, spart,
                                                              cnt_range, cnt_before);
    main_kernel<<<NGRP * JRANGES, 1024, 0, stream>>>(inputs, lab, spart, cnt_before, out);
}

// Round 7
// 235.018 us; speedup vs baseline: 1.5427x; 1.5427x over previous
//
#include <hip/hip_runtime.h>
#include <hip/hip_bf16.h>

#define N_TOK 16384
#define DIM 2048
#define KCLS 64
#define JRANGES 32
#define RANGE 512   // N_TOK / JRANGES
#define KC 128      // GEMM K-chunk
#define EPS 1e-8f

typedef short bf16x8 __attribute__((ext_vector_type(8)));
typedef float f32x4 __attribute__((ext_vector_type(4)));

__device__ __forceinline__ unsigned short f2bf(float f) {
    unsigned u = __float_as_uint(f);
    u += 0x7fffu + ((u >> 16) & 1u);
    return (unsigned short)(u >> 16);
}
__device__ __forceinline__ float bf2f(unsigned short s) {
    return __uint_as_float(((unsigned)s) << 16);
}

__device__ __forceinline__ float dpp_sum64(float x) {
    x += __int_as_float(__builtin_amdgcn_update_dpp(0, __float_as_int(x), 0x111, 0xf, 0xf, true));
    x += __int_as_float(__builtin_amdgcn_update_dpp(0, __float_as_int(x), 0x112, 0xf, 0xf, true));
    x += __int_as_float(__builtin_amdgcn_update_dpp(0, __float_as_int(x), 0x114, 0xf, 0xf, true));
    x += __int_as_float(__builtin_amdgcn_update_dpp(0, __float_as_int(x), 0x118, 0xf, 0xf, true));
    x += __int_as_float(__builtin_amdgcn_update_dpp(0, __float_as_int(x), 0x142, 0xf, 0xf, true));
    x += __int_as_float(__builtin_amdgcn_update_dpp(0, __float_as_int(x), 0x143, 0xf, 0xf, true));
    return x;  // valid in lane 63 only
}

// ---------------------------------------------------------------------------
// Kernel 0: sniff labels dtype (int64 vs int32) per block, normalize to int32.
__global__ __launch_bounds__(256) void fix_labels_kernel(
    const int* __restrict__ raw, int* __restrict__ lab) {
    __shared__ int not64;
    int t = threadIdx.x, b = blockIdx.x;
    if (t == 0) not64 = 0;
    __syncthreads();
    int n0 = b * 256 + t;
    int lo = raw[2 * n0], hi = raw[2 * n0 + 1];
    if (hi != 0 || lo < 0 || lo >= KCLS) atomicOr(&not64, 1);
    __syncthreads();
    lab[n0] = not64 ? raw[n0] : raw[2 * n0];
}

// ---------------------------------------------------------------------------
// Kernel 1: per-(range, class) partial sum of class-k token vectors.
// bid = k*32 + j -> bid%8 == j%8: same-range blocks share an XCD L2.
__global__ __launch_bounds__(256) void partials_kernel(
    const float* __restrict__ x, const int* __restrict__ lab,
    float* __restrict__ spart, int* __restrict__ cnt_range) {
    int bid = blockIdx.x;
    int j = bid & 31, k = bid >> 5;
    int t = threadIdx.x;
    __shared__ int ll[RANGE];
    __shared__ short ml[RANGE];
    __shared__ int nm_s;
    for (int i = t; i < RANGE; i += 256) ll[i] = lab[j * RANGE + i];
    __syncthreads();
    if (t == 0) {
        int nm = 0;
        for (int i = 0; i < RANGE; i++)
            if (ll[i] == k) ml[nm++] = (short)i;
        nm_s = nm;
        cnt_range[j * KCLS + k] = nm;
    }
    __syncthreads();
    int nm = nm_s;
    float4 a = {0, 0, 0, 0}, b4 = {0, 0, 0, 0};
    for (int m = 0; m < nm; m++) {
        const float* r = x + (size_t)(j * RANGE + (int)ml[m]) * DIM;
        float4 xa = *(const float4*)(r + t * 4);
        float4 xb = *(const float4*)(r + 1024 + t * 4);
        a.x += xa.x; a.y += xa.y; a.z += xa.z; a.w += xa.w;
        b4.x += xb.x; b4.y += xb.y; b4.z += xb.z; b4.w += xb.w;
    }
    float* dst = spart + ((size_t)j * KCLS + k) * DIM;
    *(float4*)(dst + t * 4) = a;
    *(float4*)(dst + 1024 + t * 4) = b4;
}

// ---------------------------------------------------------------------------
// Kernel 2: in-place exclusive scan over ranges -> boundary snapshots.
__global__ __launch_bounds__(256) void scan_kernel(
    const float* __restrict__ avgs, float* __restrict__ spart,
    const int* __restrict__ cnt_range, int* __restrict__ cnt_before) {
    int t = blockIdx.x * 256 + threadIdx.x;  // 32768 threads
    int k = t >> 9;
    int d4 = t & 511;
    int d = d4 * 4;
    float4 run = {0, 0, 0, 0};
    int cb = 0;
    float4 init = *(const float4*)(avgs + (size_t)k * DIM + d);
    for (int j = 0; j < JRANGES; j++) {
        size_t idx = ((size_t)j * KCLS + k) * DIM + d;
        float4 part = *(const float4*)(spart + idx);
        float4 w = (cb == 0) ? init : run;
        *(float4*)(spart + idx) = w;
        if (d4 == 0) cnt_before[j * KCLS + k] = cb;
        run.x += part.x; run.y += part.y; run.z += part.z; run.w += part.w;
        cb += cnt_range[j * KCLS + k];
    }
}

// ---------------------------------------------------------------------------
// Kernel 3: exact fp32 ||snapshot||^2 per (range, class). One wave per row.
__global__ __launch_bounds__(64) void snapnorm_kernel(
    const float* __restrict__ spart, float* __restrict__ n2snap) {
    int b = blockIdx.x;            // j*64 + k
    int lane = threadIdx.x;
    const float* row = spart + (size_t)b * DIM;
    float s = 0.f;
#pragma unroll
    for (int i = 0; i < 8; i++) {
        float4 v = *(const float4*)(row + i * 256 + lane * 4);
        s = fmaf(v.x, v.x, s); s = fmaf(v.y, v.y, s);
        s = fmaf(v.z, v.z, s); s = fmaf(v.w, v.w, s);
    }
    s = dpp_sum64(s);
    if (lane == 63) n2snap[b] = s;
}

// ---------------------------------------------------------------------------
// Kernel 4: per-range GEMMs via bf16 MFMA.
// tt 0..9: G-tiles (I>=J, 128x128) of G = X·X^T (lower triangle + diag).
// tt 10..13: D-tiles (128 tokens x 64 classes) of D0 = X·S^T.
// Diag G-tiles also emit exact fp32 diagonal -> vnorm2.
// bid = tt*32 + j -> bid%8 == j%8 (XCD locality for the range's X panels).
__global__ __launch_bounds__(512, 4) void gemm_kernel(
    const float* __restrict__ x, const float* __restrict__ spart,
    float* __restrict__ D0, unsigned short* __restrict__ Gbf,
    float* __restrict__ vnorm2) {
    __shared__ short PI[128 * KC];   // 32 KB
    __shared__ short PJ[128 * KC];   // 32 KB
    static const char TIa[14] = {0,1,1,2,2,2,3,3,3,3, 0,1,2,3};
    static const char TJa[14] = {0,0,1,0,1,2,0,1,2,3, 0,0,0,0};

    int bid = blockIdx.x;
    int j = bid & 31;
    int tt = bid >> 5;
    int I = TIa[tt], J = TJa[tt];
    bool isD = (tt >= 10);
    bool diag = (!isD) && (I == J);
    int start = j * RANGE;
    int t = threadIdx.x, lane = t & 63, w = t >> 6;
    int rw = w & 3, cw = w >> 2;
    int NCF = isD ? 2 : 4;
    int colbase = isD ? cw * 32 : cw * 64;

    f32x4 acc[2][4];
#pragma unroll
    for (int a = 0; a < 2; a++)
#pragma unroll
        for (int b = 0; b < 4; b++) acc[a][b] = (f32x4){0.f, 0.f, 0.f, 0.f};

    const float* srcI = x + (size_t)(start + I * 128) * DIM;
    const float* srcJ = isD ? (spart + (size_t)(j * KCLS) * DIM)
                            : (x + (size_t)(start + J * 128) * DIM);
    int nJrows = isD ? 64 : 128;

    for (int kc = 0; kc < DIM / KC; kc++) {   // 16 chunks
#pragma unroll
        for (int i = 0; i < 8; i++) {
            int e = 4 * (t + 512 * i);
            int row = e >> 7, col = e & 127;
            float4 v = *(const float4*)(srcI + (size_t)row * DIM + kc * KC + col);
            __hip_bfloat162 lo = __float22bfloat162_rn(make_float2(v.x, v.y));
            __hip_bfloat162 hi = __float22bfloat162_rn(make_float2(v.z, v.w));
            int idx = row * KC + (((col & ~7) ^ ((row & 7) << 3)) | (col & 7));
            *(uint2*)&PI[idx] = make_uint2(*(unsigned*)&lo, *(unsigned*)&hi);
        }
        if (!diag) {
#pragma unroll
            for (int i = 0; i < 8; i++) {
                int e = 4 * (t + 512 * i);
                int row = e >> 7, col = e & 127;
                if (row < nJrows) {
                    float4 v = *(const float4*)(srcJ + (size_t)row * DIM + kc * KC + col);
                    __hip_bfloat162 lo = __float22bfloat162_rn(make_float2(v.x, v.y));
                    __hip_bfloat162 hi = __float22bfloat162_rn(make_float2(v.z, v.w));
                    int idx = row * KC + (((col & ~7) ^ ((row & 7) << 3)) | (col & 7));
                    *(uint2*)&PJ[idx] = make_uint2(*(unsigned*)&lo, *(unsigned*)&hi);
                }
            }
        }
        __syncthreads();
        const short* PB = diag ? PI : PJ;
#pragma unroll
        for (int kk = 0; kk < 4; kk++) {
            int kb = kk * 32 + (lane >> 4) * 8;
            int ra = rw * 32 + (lane & 15);
            bf16x8 a0 = *(const bf16x8*)&PI[ra * KC + (kb ^ ((ra & 7) << 3))];
            int ra1 = ra + 16;
            bf16x8 a1 = *(const bf16x8*)&PI[ra1 * KC + (kb ^ ((ra1 & 7) << 3))];
#pragma unroll
            for (int f = 0; f < 4; f++) {
                if (f < NCF) {
                    int rb = colbase + f * 16 + (lane & 15);
                    bf16x8 bb = *(const bf16x8*)&PB[rb * KC + (kb ^ ((rb & 7) << 3))];
                    acc[0][f] = __builtin_amdgcn_mfma_f32_16x16x32_bf16(a0, bb, acc[0][f], 0, 0, 0);
                    acc[1][f] = __builtin_amdgcn_mfma_f32_16x16x32_bf16(a1, bb, acc[1][f], 0, 0, 0);
                }
            }
        }
        __syncthreads();
    }

    if (!isD) {
        size_t gbase = (size_t)j * (512 * 512);
#pragma unroll
        for (int rf = 0; rf < 2; rf++)
#pragma unroll
            for (int f = 0; f < 4; f++)
#pragma unroll
                for (int r = 0; r < 4; r++) {
                    int lrow = I * 128 + rw * 32 + rf * 16 + (lane >> 4) * 4 + r;
                    int lcol = J * 128 + colbase + f * 16 + (lane & 15);
                    float vv = acc[rf][f][r];
                    Gbf[gbase + (size_t)lrow * 512 + lcol] = f2bf(vv);
                    if (diag && lrow == lcol) vnorm2[start + lrow] = vv;
                }
    } else {
#pragma unroll
        for (int rf = 0; rf < 2; rf++)
#pragma unroll
            for (int f = 0; f < 2; f++)
#pragma unroll
                for (int r = 0; r < 4; r++) {
                    int grow = start + I * 128 + rw * 32 + rf * 16 + (lane >> 4) * 4 + r;
                    int gcol = colbase + f * 16 + (lane & 15);
                    D0[(size_t)grow * KCLS + gcol] = acc[rf][f][r];
                }
    }
}

// ---------------------------------------------------------------------------
// Kernel 5: finalize. Block = (range j, class-group g of 8 classes).
// Reconstructs exact sequential semantics from D0/G/vnorm2/n2snap:
//   dot(t,c) = [keep]*D0[t][c] + sum_{events e<t of c} G[t][e]
//   n2 stages per class via n2 += 2*rd + ||x_e||^2 (rd from D0 + Gram sums);
//   virgin classes (cnt_before==0): first event replaces the prototype.
__global__ __launch_bounds__(512) void finalize_kernel(
    const int* __restrict__ lab, const float* __restrict__ D0,
    const unsigned short* __restrict__ Gbf, const float* __restrict__ vnorm2,
    const float* __restrict__ n2snap, const int* __restrict__ cnt_before,
    float* __restrict__ out) {
    __shared__ unsigned char lbl[RANGE];
    __shared__ short evl[RANGE];
    __shared__ short evcnt[8];
    __shared__ short evoff[9];
    __shared__ float invna[RANGE + 8];
    __shared__ unsigned char vgs[8];

    int bid = blockIdx.x;
    int g = bid >> 5, j = bid & 31;
    int g8 = g * 8;
    int start = j * RANGE;
    int t = threadIdx.x;
    lbl[t] = (unsigned char)lab[start + t];
    __syncthreads();
    if (t < 8) {
        int c = g8 + t, m = 0;
        for (int i = 0; i < RANGE; i++) m += (lbl[i] == c) ? 1 : 0;
        evcnt[t] = (short)m;
        vgs[t] = (cnt_before[j * KCLS + c] == 0) ? 1 : 0;
    }
    __syncthreads();
    if (t == 0) {
        int s = 0;
        for (int c = 0; c < 8; c++) { evoff[c] = (short)s; s += evcnt[c]; }
        evoff[8] = (short)s;
    }
    __syncthreads();
    if (t < 8) {
        int c = g8 + t;
        int o = evoff[t];
        for (int i = 0; i < RANGE; i++)
            if (lbl[i] == c) evl[o++] = (short)i;
        // n2 stages
        o = evoff[t];
        int m = evcnt[t];
        int vg = vgs[t];
        float n2 = n2snap[j * KCLS + c];
        int so = o + t;
        invna[so] = 1.0f / fmaxf(sqrtf(n2), EPS);
        for (int i = 1; i <= m; i++) {
            int e = evl[o + i - 1];
            float xn2 = vnorm2[start + e];
            if (vg && i == 1) {
                n2 = xn2;
            } else {
                float rd = vg ? 0.f : D0[(size_t)(start + e) * KCLS + c];
                const unsigned short* gr = Gbf + (size_t)j * 262144 + (size_t)e * 512;
                for (int u = 0; u < i - 1; u++) rd += bf2f(gr[evl[o + u]]);
                n2 += 2.f * rd + xn2;
            }
            invna[so + i] = 1.0f / fmaxf(sqrtf(n2), EPS);
        }
    }
    __syncthreads();
    // output phase: thread t = token t
    {
        float4 d0a = *(const float4*)&D0[(size_t)(start + t) * KCLS + g8];
        float4 d0b = *(const float4*)&D0[(size_t)(start + t) * KCLS + g8 + 4];
        float d0[8] = {d0a.x, d0a.y, d0a.z, d0a.w, d0b.x, d0b.y, d0b.z, d0b.w};
        float nvinv = 1.0f / fmaxf(sqrtf(vnorm2[start + t]), EPS);
        const unsigned short* gr = Gbf + (size_t)j * 262144 + (size_t)t * 512;
        float o[8];
#pragma unroll
        for (int c = 0; c < 8; c++) {
            int off = evoff[c], m = evcnt[c];
            float corr = 0.f;
            int i = 0;
            while (i < m) {
                int e = evl[off + i];
                if (e >= t) break;
                corr += bf2f(gr[e]);
                i++;
            }
            float dot = (vgs[c] && i > 0) ? corr : (d0[c] + corr);
            o[c] = dot * invna[off + c + i] * nvinv;
        }
        float4 oa = {o[0], o[1], o[2], o[3]};
        float4 ob = {o[4], o[5], o[6], o[7]};
        float* op = &out[(size_t)(start + t) * KCLS + g8];
        *(float4*)op = oa;
        *(float4*)(op + 4) = ob;
    }
}

// ---------------------------------------------------------------------------
extern "C" void kernel_launch(void* const* d_in, const int* in_sizes, int n_in,
                              void* d_out, int out_size, void* d_ws, size_t ws_size,
                              hipStream_t stream) {
    const float* inputs = (const float*)d_in[0];
    const float* class_avgs = (const float*)d_in[1];
    const int* labels_raw = (const int*)d_in[2];
    float* out = (float*)d_out;
    char* ws = (char*)d_ws;

    size_t off = 0;
    int* lab = (int*)(ws + off);          off += (size_t)N_TOK * 4;
    int* cnt_range = (int*)(ws + off);    off += (size_t)JRANGES * KCLS * 4;
    int* cnt_before = (int*)(ws + off);   off += (size_t)JRANGES * KCLS * 4;
    float* n2snap = (float*)(ws + off);   off += (size_t)JRANGES * KCLS * 4;
    float* vnorm2 = (float*)(ws + off);   off += (size_t)N_TOK * 4;
    off = (off + 255) & ~(size_t)255;
    float* spart = (float*)(ws + off);    off += (size_t)JRANGES * KCLS * DIM * 4;  // 16 MB
    float* D0 = (float*)(ws + off);       off += (size_t)N_TOK * KCLS * 4;          // 4 MB
    unsigned short* Gbf = (unsigned short*)(ws + off);
    off += (size_t)JRANGES * 512 * 512 * 2;                                         // 16 MB

    fix_labels_kernel<<<N_TOK / 256, 256, 0, stream>>>(labels_raw, lab);
    partials_kernel<<<JRANGES * KCLS, 256, 0, stream>>>(inputs, lab, spart, cnt_range);
    scan_kernel<<<(KCLS * (DIM / 4)) / 256, 256, 0, stream>>>(class_avgs, spart,
                                                              cnt_range, cnt_before);
    snapnorm_kernel<<<JRANGES * KCLS, 64, 0, stream>>>(spart, n2snap);
    gemm_kernel<<<14 * JRANGES, 512, 0, stream>>>(inputs, spart, D0, Gbf, vnorm2);
    finalize_kernel<<<8 * JRANGES, 512, 0, stream>>>(lab, D0, Gbf, vnorm2, n2snap,
                                                     cnt_before, out);
}

// Round 8
// 205.743 us; speedup vs baseline: 1.7622x; 1.1423x over previous
//
#include <hip/hip_runtime.h>
#include <hip/hip_bf16.h>

#define N_TOK 16384
#define DIM 2048
#define KCLS 64
#define JRANGES 32
#define RANGE 512   // N_TOK / JRANGES
#define KC 64       // GEMM K-chunk (bf16, double-buffered)
#define EPS 1e-8f

typedef short bf16x8 __attribute__((ext_vector_type(8)));
typedef unsigned short u16x8 __attribute__((ext_vector_type(8)));
typedef float f32x4 __attribute__((ext_vector_type(4)));

__device__ __forceinline__ unsigned short f2bf(float f) {
    unsigned u = __float_as_uint(f);
    u += 0x7fffu + ((u >> 16) & 1u);
    return (unsigned short)(u >> 16);
}
__device__ __forceinline__ float bf2f(unsigned short s) {
    return __uint_as_float(((unsigned)s) << 16);
}

__device__ __forceinline__ float dpp_sum64(float x) {
    x += __int_as_float(__builtin_amdgcn_update_dpp(0, __float_as_int(x), 0x111, 0xf, 0xf, true));
    x += __int_as_float(__builtin_amdgcn_update_dpp(0, __float_as_int(x), 0x112, 0xf, 0xf, true));
    x += __int_as_float(__builtin_amdgcn_update_dpp(0, __float_as_int(x), 0x114, 0xf, 0xf, true));
    x += __int_as_float(__builtin_amdgcn_update_dpp(0, __float_as_int(x), 0x118, 0xf, 0xf, true));
    x += __int_as_float(__builtin_amdgcn_update_dpp(0, __float_as_int(x), 0x142, 0xf, 0xf, true));
    x += __int_as_float(__builtin_amdgcn_update_dpp(0, __float_as_int(x), 0x143, 0xf, 0xf, true));
    return x;  // valid in lane 63 only
}

// ---------------------------------------------------------------------------
// Kernel 0: sniff labels dtype (int64 vs int32) per block, normalize to int32.
__global__ __launch_bounds__(256) void fix_labels_kernel(
    const int* __restrict__ raw, int* __restrict__ lab) {
    __shared__ int not64;
    int t = threadIdx.x, b = blockIdx.x;
    if (t == 0) not64 = 0;
    __syncthreads();
    int n0 = b * 256 + t;
    int lo = raw[2 * n0], hi = raw[2 * n0 + 1];
    if (hi != 0 || lo < 0 || lo >= KCLS) atomicOr(&not64, 1);
    __syncthreads();
    lab[n0] = not64 ? raw[n0] : raw[2 * n0];
}

// ---------------------------------------------------------------------------
// Kernel 1: prep — cast X to bf16 (row-major) + exact fp32 token norms.
// One wave per token; streaming, ~192 MB total traffic.
__global__ __launch_bounds__(256) void prep_kernel(
    const float* __restrict__ x, unsigned short* __restrict__ xb,
    float* __restrict__ vnorm2) {
    int w4 = threadIdx.x >> 6, lane = threadIdx.x & 63;
    int n = blockIdx.x * 4 + w4;
    const float* v = x + (size_t)n * DIM;
    unsigned short* o = xb + (size_t)n * DIM;
    float p = 0.f;
#pragma unroll
    for (int it = 0; it < 8; it++) {
        float4 a = *(const float4*)(v + it * 256 + lane * 4);
        p = fmaf(a.x, a.x, p); p = fmaf(a.y, a.y, p);
        p = fmaf(a.z, a.z, p); p = fmaf(a.w, a.w, p);
        ushort4 h = make_ushort4(f2bf(a.x), f2bf(a.y), f2bf(a.z), f2bf(a.w));
        *(ushort4*)(o + it * 256 + lane * 4) = h;
    }
    p = dpp_sum64(p);
    if (lane == 63) vnorm2[n] = p;
}

// ---------------------------------------------------------------------------
// Kernel 2: per-(range, class) partial sum of class-k token vectors (bf16 in,
// fp32 accum). bid = k*32 + j -> bid%8 == j%8 (XCD locality).
__global__ __launch_bounds__(256) void partials_kernel(
    const unsigned short* __restrict__ xb, const int* __restrict__ lab,
    float* __restrict__ spart, int* __restrict__ cnt_range) {
    int bid = blockIdx.x;
    int j = bid & 31, k = bid >> 5;
    int t = threadIdx.x;
    __shared__ int ll[RANGE];
    __shared__ short ml[RANGE];
    __shared__ int nm_s;
    for (int i = t; i < RANGE; i += 256) ll[i] = lab[j * RANGE + i];
    __syncthreads();
    if (t == 0) {
        int nm = 0;
        for (int i = 0; i < RANGE; i++)
            if (ll[i] == k) ml[nm++] = (short)i;
        nm_s = nm;
        cnt_range[j * KCLS + k] = nm;
    }
    __syncthreads();
    int nm = nm_s;
    float acc[8] = {0, 0, 0, 0, 0, 0, 0, 0};
    for (int m = 0; m < nm; m++) {
        const unsigned short* r = xb + (size_t)(j * RANGE + (int)ml[m]) * DIM + t * 8;
        u16x8 hv = *(const u16x8*)r;
#pragma unroll
        for (int i = 0; i < 8; i++) acc[i] += bf2f(hv[i]);
    }
    float* dst = spart + ((size_t)j * KCLS + k) * DIM + t * 8;
    *(float4*)dst = make_float4(acc[0], acc[1], acc[2], acc[3]);
    *(float4*)(dst + 4) = make_float4(acc[4], acc[5], acc[6], acc[7]);
}

// ---------------------------------------------------------------------------
// Kernel 3: in-place exclusive scan over ranges -> boundary snapshots;
// also emits bf16 snapshot mirror Sb for the D0 MFMA.
__global__ __launch_bounds__(256) void scan_kernel(
    const float* __restrict__ avgs, float* __restrict__ spart,
    unsigned short* __restrict__ Sb,
    const int* __restrict__ cnt_range, int* __restrict__ cnt_before) {
    int t = blockIdx.x * 256 + threadIdx.x;  // 32768 threads
    int k = t >> 9;
    int d4 = t & 511;
    int d = d4 * 4;
    float4 run = {0, 0, 0, 0};
    int cb = 0;
    float4 init = *(const float4*)(avgs + (size_t)k * DIM + d);
    for (int j = 0; j < JRANGES; j++) {
        size_t idx = ((size_t)j * KCLS + k) * DIM + d;
        float4 part = *(const float4*)(spart + idx);
        float4 w = (cb == 0) ? init : run;
        *(float4*)(spart + idx) = w;
        *(ushort4*)(Sb + idx) = make_ushort4(f2bf(w.x), f2bf(w.y), f2bf(w.z), f2bf(w.w));
        if (d4 == 0) cnt_before[j * KCLS + k] = cb;
        run.x += part.x; run.y += part.y; run.z += part.z; run.w += part.w;
        cb += cnt_range[j * KCLS + k];
    }
}

// ---------------------------------------------------------------------------
// Kernel 4: exact fp32 ||snapshot||^2 per (range, class). One wave per row.
__global__ __launch_bounds__(64) void snapnorm_kernel(
    const float* __restrict__ spart, float* __restrict__ n2snap) {
    int b = blockIdx.x;            // j*64 + k
    int lane = threadIdx.x;
    const float* row = spart + (size_t)b * DIM;
    float s = 0.f;
#pragma unroll
    for (int i = 0; i < 8; i++) {
        float4 v = *(const float4*)(row + i * 256 + lane * 4);
        s = fmaf(v.x, v.x, s); s = fmaf(v.y, v.y, s);
        s = fmaf(v.z, v.z, s); s = fmaf(v.w, v.w, s);
    }
    s = dpp_sum64(s);
    if (lane == 63) n2snap[b] = s;
}

// ---------------------------------------------------------------------------
// stage one bf16 panel K-chunk into LDS via global_load_lds.
// LDS layout: [rows][64] bf16 with 16B-group XOR swizzle g^=(row&7); the XOR
// is applied to the GLOBAL source address (linear LDS dest = m173 pattern).
// nunits: 1024 (128 rows) or 512 (64 rows); 8 units (16B) per row.
__device__ __forceinline__ void stage_panel(
    const unsigned short* __restrict__ src, short* dst, int nunits,
    int t, int kcoff) {
#pragma unroll
    for (int i = 0; i < 2; i++) {
        int u = t + 512 * i;
        if (u < nunits) {
            int row = u >> 3, gsw = u & 7;
            int g = gsw ^ (row & 7);
            const unsigned short* s = src + (size_t)row * DIM + kcoff + g * 8;
            __builtin_amdgcn_global_load_lds(
                (__attribute__((address_space(1))) void*)s,
                (__attribute__((address_space(3))) void*)(dst + u * 8),
                16, 0, 0);
        }
    }
}

// ---------------------------------------------------------------------------
// Kernel 5: per-range GEMMs via bf16 MFMA, bf16 inputs, double-buffered
// global_load_lds staging (KC=64), one barrier per chunk.
// tt 0..9: G-tiles (I>=J, 128x128) of G = X·X^T; tt 10..13: D-tiles
// (128 tokens x 64 classes) of D0 = X·S^T. bid = tt*32 + j (XCD locality).
__global__ __launch_bounds__(512, 4) void gemm_kernel(
    const unsigned short* __restrict__ xb, const unsigned short* __restrict__ Sb,
    float* __restrict__ D0, unsigned short* __restrict__ Gbf) {
    __shared__ short PI[2][128 * KC];   // 2 x 16 KB
    __shared__ short PJ[2][128 * KC];   // 2 x 16 KB
    static const char TIa[14] = {0,1,1,2,2,2,3,3,3,3, 0,1,2,3};
    static const char TJa[14] = {0,0,1,0,1,2,0,1,2,3, 0,0,0,0};

    int bid = blockIdx.x;
    int j = bid & 31;
    int tt = bid >> 5;
    int I = TIa[tt], J = TJa[tt];
    bool isD = (tt >= 10);
    bool diag = (!isD) && (I == J);
    int start = j * RANGE;
    int t = threadIdx.x, lane = t & 63, w = t >> 6;
    int rw = w & 3, cw = w >> 2;
    int NCF = isD ? 2 : 4;
    int colbase = isD ? cw * 32 : cw * 64;

    f32x4 acc[2][4];
#pragma unroll
    for (int a = 0; a < 2; a++)
#pragma unroll
        for (int b = 0; b < 4; b++) acc[a][b] = (f32x4){0.f, 0.f, 0.f, 0.f};

    const unsigned short* srcI = xb + (size_t)(start + I * 128) * DIM;
    const unsigned short* srcJ = isD ? (Sb + (size_t)(j * KCLS) * DIM)
                                     : (xb + (size_t)(start + J * 128) * DIM);
    int nJu = isD ? 512 : 1024;

    // prologue: stage chunk 0 into buffer 0
    stage_panel(srcI, PI[0], 1024, t, 0);
    if (!diag) stage_panel(srcJ, PJ[0], nJu, t, 0);
    __syncthreads();

    for (int kc = 0; kc < DIM / KC; kc++) {   // 32 chunks
        int cur = kc & 1;
        if (kc + 1 < DIM / KC) {  // issue next chunk into other buffer
            stage_panel(srcI, PI[cur ^ 1], 1024, t, (kc + 1) * KC);
            if (!diag) stage_panel(srcJ, PJ[cur ^ 1], nJu, t, (kc + 1) * KC);
        }
        const short* PA = PI[cur];
        const short* PB = diag ? PI[cur] : PJ[cur];
#pragma unroll
        for (int kk = 0; kk < 2; kk++) {
            int kb = kk * 32 + (lane >> 4) * 8;
            int ra = rw * 32 + (lane & 15);
            bf16x8 a0 = *(const bf16x8*)&PA[ra * KC + (kb ^ ((ra & 7) << 3))];
            int ra1 = ra + 16;
            bf16x8 a1 = *(const bf16x8*)&PA[ra1 * KC + (kb ^ ((ra1 & 7) << 3))];
#pragma unroll
            for (int f = 0; f < 4; f++) {
                if (f < NCF) {
                    int rb = colbase + f * 16 + (lane & 15);
                    bf16x8 bb = *(const bf16x8*)&PB[rb * KC + (kb ^ ((rb & 7) << 3))];
                    acc[0][f] = __builtin_amdgcn_mfma_f32_16x16x32_bf16(a0, bb, acc[0][f], 0, 0, 0);
                    acc[1][f] = __builtin_amdgcn_mfma_f32_16x16x32_bf16(a1, bb, acc[1][f], 0, 0, 0);
                }
            }
        }
        __syncthreads();  // reads of cur done + next chunk fully staged
    }

    if (!isD) {
        size_t gbase = (size_t)j * (512 * 512);
#pragma unroll
        for (int rf = 0; rf < 2; rf++)
#pragma unroll
            for (int f = 0; f < 4; f++)
#pragma unroll
                for (int r = 0; r < 4; r++) {
                    int lrow = I * 128 + rw * 32 + rf * 16 + (lane >> 4) * 4 + r;
                    int lcol = J * 128 + colbase + f * 16 + (lane & 15);
                    Gbf[gbase + (size_t)lrow * 512 + lcol] = f2bf(acc[rf][f][r]);
                }
    } else {
#pragma unroll
        for (int rf = 0; rf < 2; rf++)
#pragma unroll
            for (int f = 0; f < 2; f++)
#pragma unroll
                for (int r = 0; r < 4; r++) {
                    int grow = start + I * 128 + rw * 32 + rf * 16 + (lane >> 4) * 4 + r;
                    int gcol = colbase + f * 16 + (lane & 15);
                    D0[(size_t)grow * KCLS + gcol] = acc[rf][f][r];
                }
    }
}

// ---------------------------------------------------------------------------
// Kernel 6: finalize. Block = (range j, class-group g of 8 classes).
//   dot(t,c) = [keep]*D0[t][c] + sum_{events e<t of c} G[t][e]
//   n2 stages per class via n2 += 2*rd + ||x_e||^2; virgin classes
//   (cnt_before==0): first event replaces the prototype.
__global__ __launch_bounds__(512) void finalize_kernel(
    const int* __restrict__ lab, const float* __restrict__ D0,
    const unsigned short* __restrict__ Gbf, const float* __restrict__ vnorm2,
    const float* __restrict__ n2snap, const int* __restrict__ cnt_before,
    float* __restrict__ out) {
    __shared__ unsigned char lbl[RANGE];
    __shared__ short evl[RANGE];
    __shared__ short evcnt[8];
    __shared__ short evoff[9];
    __shared__ float invna[RANGE + 8];
    __shared__ unsigned char vgs[8];

    int bid = blockIdx.x;
    int g = bid >> 5, j = bid & 31;
    int g8 = g * 8;
    int start = j * RANGE;
    int t = threadIdx.x;
    lbl[t] = (unsigned char)lab[start + t];
    __syncthreads();
    if (t < 8) {
        int c = g8 + t, m = 0;
        for (int i = 0; i < RANGE; i++) m += (lbl[i] == c) ? 1 : 0;
        evcnt[t] = (short)m;
        vgs[t] = (cnt_before[j * KCLS + c] == 0) ? 1 : 0;
    }
    __syncthreads();
    if (t == 0) {
        int s = 0;
        for (int c = 0; c < 8; c++) { evoff[c] = (short)s; s += evcnt[c]; }
        evoff[8] = (short)s;
    }
    __syncthreads();
    if (t < 8) {
        int c = g8 + t;
        int o = evoff[t];
        for (int i = 0; i < RANGE; i++)
            if (lbl[i] == c) evl[o++] = (short)i;
        o = evoff[t];
        int m = evcnt[t];
        int vg = vgs[t];
        float n2 = n2snap[j * KCLS + c];
        int so = o + t;
        invna[so] = 1.0f / fmaxf(sqrtf(n2), EPS);
        for (int i = 1; i <= m; i++) {
            int e = evl[o + i - 1];
            float xn2 = vnorm2[start + e];
            if (vg && i == 1) {
                n2 = xn2;
            } else {
                float rd = vg ? 0.f : D0[(size_t)(start + e) * KCLS + c];
                const unsigned short* gr = Gbf + (size_t)j * 262144 + (size_t)e * 512;
                for (int u = 0; u < i - 1; u++) rd += bf2f(gr[evl[o + u]]);
                n2 += 2.f * rd + xn2;
            }
            invna[so + i] = 1.0f / fmaxf(sqrtf(n2), EPS);
        }
    }
    __syncthreads();
    {
        float4 d0a = *(const float4*)&D0[(size_t)(start + t) * KCLS + g8];
        float4 d0b = *(const float4*)&D0[(size_t)(start + t) * KCLS + g8 + 4];
        float d0[8] = {d0a.x, d0a.y, d0a.z, d0a.w, d0b.x, d0b.y, d0b.z, d0b.w};
        float nvinv = 1.0f / fmaxf(sqrtf(vnorm2[start + t]), EPS);
        const unsigned short* gr = Gbf + (size_t)j * 262144 + (size_t)t * 512;
        float o[8];
#pragma unroll
        for (int c = 0; c < 8; c++) {
            int off = evoff[c], m = evcnt[c];
            float corr = 0.f;
            int i = 0;
            while (i < m) {
                int e = evl[off + i];
                if (e >= t) break;
                corr += bf2f(gr[e]);
                i++;
            }
            float dot = (vgs[c] && i > 0) ? corr : (d0[c] + corr);
            o[c] = dot * invna[off + c + i] * nvinv;
        }
        float4 oa = {o[0], o[1], o[2], o[3]};
        float4 ob = {o[4], o[5], o[6], o[7]};
        float* op = &out[(size_t)(start + t) * KCLS + g8];
        *(float4*)op = oa;
        *(float4*)(op + 4) = ob;
    }
}

// ---------------------------------------------------------------------------
extern "C" void kernel_launch(void* const* d_in, const int* in_sizes, int n_in,
                              void* d_out, int out_size, void* d_ws, size_t ws_size,
                              hipStream_t stream) {
    const float* inputs = (const float*)d_in[0];
    const float* class_avgs = (const float*)d_in[1];
    const int* labels_raw = (const int*)d_in[2];
    float* out = (float*)d_out;
    char* ws = (char*)d_ws;

    size_t off = 0;
    int* lab = (int*)(ws + off);          off += (size_t)N_TOK * 4;
    int* cnt_range = (int*)(ws + off);    off += (size_t)JRANGES * KCLS * 4;
    int* cnt_before = (int*)(ws + off);   off += (size_t)JRANGES * KCLS * 4;
    float* n2snap = (float*)(ws + off);   off += (size_t)JRANGES * KCLS * 4;
    float* vnorm2 = (float*)(ws + off);   off += (size_t)N_TOK * 4;
    off = (off + 255) & ~(size_t)255;
    unsigned short* Xb = (unsigned short*)(ws + off);
    off += (size_t)N_TOK * DIM * 2;                                   // 64 MB
    unsigned short* Sb = (unsigned short*)(ws + off);
    off += (size_t)JRANGES * KCLS * DIM * 2;                          // 8 MB
    float* D0 = (float*)(ws + off);       off += (size_t)N_TOK * KCLS * 4;  // 4 MB
    float* spart = (float*)(ws + off);    // 16 MB, dead after snapnorm
    unsigned short* Gbf = (unsigned short*)spart;  // overlay (16 MB)

    fix_labels_kernel<<<N_TOK / 256, 256, 0, stream>>>(labels_raw, lab);
    prep_kernel<<<N_TOK / 4, 256, 0, stream>>>(inputs, Xb, vnorm2);
    partials_kernel<<<JRANGES * KCLS, 256, 0, stream>>>(Xb, lab, spart, cnt_range);
    scan_kernel<<<(KCLS * (DIM / 4)) / 256, 256, 0, stream>>>(class_avgs, spart, Sb,
                                                              cnt_range, cnt_before);
    snapnorm_kernel<<<JRANGES * KCLS, 64, 0, stream>>>(spart, n2snap);
    gemm_kernel<<<14 * JRANGES, 512, 0, stream>>>(Xb, Sb, D0, Gbf);
    finalize_kernel<<<8 * JRANGES, 512, 0, stream>>>(lab, D0, Gbf, vnorm2, n2snap,
                                                     cnt_before, out);
}

// Round 10
// 186.460 us; speedup vs baseline: 1.9445x; 1.1034x over previous
//
#include <hip/hip_runtime.h>
#include <hip/hip_bf16.h>

#define N_TOK 16384
#define DIM 2048
#define KCLS 64
#define JRANGES 32
#define RANGE 512   // N_TOK / JRANGES
#define KC 64       // GEMM K-chunk (bf16, double-buffered)
#define EPS 1e-8f

typedef short bf16x8 __attribute__((ext_vector_type(8)));
typedef unsigned short u16x8 __attribute__((ext_vector_type(8)));
typedef float f32x4 __attribute__((ext_vector_type(4)));

__device__ __forceinline__ unsigned short f2bf(float f) {
    unsigned u = __float_as_uint(f);
    u += 0x7fffu + ((u >> 16) & 1u);
    return (unsigned short)(u >> 16);
}
__device__ __forceinline__ float bf2f(unsigned short s) {
    return __uint_as_float(((unsigned)s) << 16);
}

__device__ __forceinline__ float dpp_sum64(float x) {
    x += __int_as_float(__builtin_amdgcn_update_dpp(0, __float_as_int(x), 0x111, 0xf, 0xf, true));
    x += __int_as_float(__builtin_amdgcn_update_dpp(0, __float_as_int(x), 0x112, 0xf, 0xf, true));
    x += __int_as_float(__builtin_amdgcn_update_dpp(0, __float_as_int(x), 0x114, 0xf, 0xf, true));
    x += __int_as_float(__builtin_amdgcn_update_dpp(0, __float_as_int(x), 0x118, 0xf, 0xf, true));
    x += __int_as_float(__builtin_amdgcn_update_dpp(0, __float_as_int(x), 0x142, 0xf, 0xf, true));
    x += __int_as_float(__builtin_amdgcn_update_dpp(0, __float_as_int(x), 0x143, 0xf, 0xf, true));
    return x;  // valid in lane 63 only
}

// ---------------------------------------------------------------------------
// Kernel 0: sniff labels dtype (int64 vs int32) per block, normalize to int32.
__global__ __launch_bounds__(256) void fix_labels_kernel(
    const int* __restrict__ raw, int* __restrict__ lab) {
    __shared__ int not64;
    int t = threadIdx.x, b = blockIdx.x;
    if (t == 0) not64 = 0;
    __syncthreads();
    int n0 = b * 256 + t;
    int lo = raw[2 * n0], hi = raw[2 * n0 + 1];
    if (hi != 0 || lo < 0 || lo >= KCLS) atomicOr(&not64, 1);
    __syncthreads();
    lab[n0] = not64 ? raw[n0] : raw[2 * n0];
}

// ---------------------------------------------------------------------------
// Kernel 1: prep — cast X to bf16 (row-major) + exact fp32 token norms.
__global__ __launch_bounds__(256) void prep_kernel(
    const float* __restrict__ x, unsigned short* __restrict__ xb,
    float* __restrict__ vnorm2) {
    int w4 = threadIdx.x >> 6, lane = threadIdx.x & 63;
    int n = blockIdx.x * 4 + w4;
    const float* v = x + (size_t)n * DIM;
    unsigned short* o = xb + (size_t)n * DIM;
    float p = 0.f;
#pragma unroll
    for (int it = 0; it < 8; it++) {
        float4 a = *(const float4*)(v + it * 256 + lane * 4);
        p = fmaf(a.x, a.x, p); p = fmaf(a.y, a.y, p);
        p = fmaf(a.z, a.z, p); p = fmaf(a.w, a.w, p);
        ushort4 h = make_ushort4(f2bf(a.x), f2bf(a.y), f2bf(a.z), f2bf(a.w));
        *(ushort4*)(o + it * 256 + lane * 4) = h;
    }
    p = dpp_sum64(p);
    if (lane == 63) vnorm2[n] = p;
}

// ---------------------------------------------------------------------------
// Kernel 2: per-(range, class) partial sum of class-k token vectors (bf16 in,
// fp32 accum). bid = k*32 + j -> bid%8 == j%8 (XCD locality).
__global__ __launch_bounds__(256) void partials_kernel(
    const unsigned short* __restrict__ xb, const int* __restrict__ lab,
    float* __restrict__ spart, int* __restrict__ cnt_range) {
    int bid = blockIdx.x;
    int j = bid & 31, k = bid >> 5;
    int t = threadIdx.x;
    __shared__ int ll[RANGE];
    __shared__ short ml[RANGE];
    __shared__ int nm_s;
    for (int i = t; i < RANGE; i += 256) ll[i] = lab[j * RANGE + i];
    __syncthreads();
    if (t == 0) {
        int nm = 0;
        for (int i = 0; i < RANGE; i++)
            if (ll[i] == k) ml[nm++] = (short)i;
        nm_s = nm;
        cnt_range[j * KCLS + k] = nm;
    }
    __syncthreads();
    int nm = nm_s;
    float acc[8] = {0, 0, 0, 0, 0, 0, 0, 0};
    for (int m = 0; m < nm; m++) {
        const unsigned short* r = xb + (size_t)(j * RANGE + (int)ml[m]) * DIM + t * 8;
        u16x8 hv = *(const u16x8*)r;
#pragma unroll
        for (int i = 0; i < 8; i++) acc[i] += bf2f(hv[i]);
    }
    float* dst = spart + ((size_t)j * KCLS + k) * DIM + t * 8;
    *(float4*)dst = make_float4(acc[0], acc[1], acc[2], acc[3]);
    *(float4*)(dst + 4) = make_float4(acc[4], acc[5], acc[6], acc[7]);
}

// ---------------------------------------------------------------------------
// Kernel 3: in-place exclusive scan over ranges -> boundary snapshots;
// also emits bf16 snapshot mirror Sb for the D0 MFMA.
__global__ __launch_bounds__(256) void scan_kernel(
    const float* __restrict__ avgs, float* __restrict__ spart,
    unsigned short* __restrict__ Sb,
    const int* __restrict__ cnt_range, int* __restrict__ cnt_before) {
    int t = blockIdx.x * 256 + threadIdx.x;  // 32768 threads
    int k = t >> 9;
    int d4 = t & 511;
    int d = d4 * 4;
    float4 run = {0, 0, 0, 0};
    int cb = 0;
    float4 init = *(const float4*)(avgs + (size_t)k * DIM + d);
    for (int j = 0; j < JRANGES; j++) {
        size_t idx = ((size_t)j * KCLS + k) * DIM + d;
        float4 part = *(const float4*)(spart + idx);
        float4 w = (cb == 0) ? init : run;
        *(float4*)(spart + idx) = w;
        *(ushort4*)(Sb + idx) = make_ushort4(f2bf(w.x), f2bf(w.y), f2bf(w.z), f2bf(w.w));
        if (d4 == 0) cnt_before[j * KCLS + k] = cb;
        run.x += part.x; run.y += part.y; run.z += part.z; run.w += part.w;
        cb += cnt_range[j * KCLS + k];
    }
}

// ---------------------------------------------------------------------------
// Kernel 4: exact fp32 ||snapshot||^2 per (range, class). One wave per row.
__global__ __launch_bounds__(64) void snapnorm_kernel(
    const float* __restrict__ spart, float* __restrict__ n2snap) {
    int b = blockIdx.x;            // j*64 + k
    int lane = threadIdx.x;
    const float* row = spart + (size_t)b * DIM;
    float s = 0.f;
#pragma unroll
    for (int i = 0; i < 8; i++) {
        float4 v = *(const float4*)(row + i * 256 + lane * 4);
        s = fmaf(v.x, v.x, s); s = fmaf(v.y, v.y, s);
        s = fmaf(v.z, v.z, s); s = fmaf(v.w, v.w, s);
    }
    s = dpp_sum64(s);
    if (lane == 63) n2snap[b] = s;
}

// ---------------------------------------------------------------------------
// stage one bf16 panel K-chunk into LDS via global_load_lds (m173 pattern:
// linear LDS dest, XOR swizzle applied to the GLOBAL source address).
__device__ __forceinline__ void stage_panel(
    const unsigned short* __restrict__ src, short* dst, int nunits,
    int t, int kcoff) {
#pragma unroll
    for (int i = 0; i < 2; i++) {
        int u = t + 512 * i;
        if (u < nunits) {
            int row = u >> 3, gsw = u & 7;
            int g = gsw ^ (row & 7);
            const unsigned short* s = src + (size_t)row * DIM + kcoff + g * 8;
            __builtin_amdgcn_global_load_lds(
                (__attribute__((address_space(1))) void*)s,
                (__attribute__((address_space(3))) void*)(dst + u * 8),
                16, 0, 0);
        }
    }
}

// ---------------------------------------------------------------------------
// Kernel 5: per-range GEMMs via bf16 MFMA, double-buffered global_load_lds
// staging (KC=64). tt 0..9: G-tiles (I>=J, 128x128) of G = X·X^T;
// tt 10..13: D-tiles (128 tokens x 64 classes) of D0 = X·S^T.
// Off-diagonal G tiles store BOTH (lrow,lcol) and the transposed (lcol,lrow)
// so finalize may read full Gram rows (rule: symmetry must be materialized,
// not assumed — the round-9 NaN was reading the unwritten upper triangle).
__global__ __launch_bounds__(512, 4) void gemm_kernel(
    const unsigned short* __restrict__ xb, const unsigned short* __restrict__ Sb,
    float* __restrict__ D0, unsigned short* __restrict__ Gbf) {
    __shared__ short PI[2][128 * KC];   // 2 x 16 KB
    __shared__ short PJ[2][128 * KC];   // 2 x 16 KB
    static const char TIa[14] = {0,1,1,2,2,2,3,3,3,3, 0,1,2,3};
    static const char TJa[14] = {0,0,1,0,1,2,0,1,2,3, 0,0,0,0};

    int bid = blockIdx.x;
    int j = bid & 31;
    int tt = bid >> 5;
    int I = TIa[tt], J = TJa[tt];
    bool isD = (tt >= 10);
    bool diag = (!isD) && (I == J);
    int start = j * RANGE;
    int t = threadIdx.x, lane = t & 63, w = t >> 6;
    int rw = w & 3, cw = w >> 2;
    int NCF = isD ? 2 : 4;
    int colbase = isD ? cw * 32 : cw * 64;

    f32x4 acc[2][4];
#pragma unroll
    for (int a = 0; a < 2; a++)
#pragma unroll
        for (int b = 0; b < 4; b++) acc[a][b] = (f32x4){0.f, 0.f, 0.f, 0.f};

    const unsigned short* srcI = xb + (size_t)(start + I * 128) * DIM;
    const unsigned short* srcJ = isD ? (Sb + (size_t)(j * KCLS) * DIM)
                                     : (xb + (size_t)(start + J * 128) * DIM);
    int nJu = isD ? 512 : 1024;

    stage_panel(srcI, PI[0], 1024, t, 0);
    if (!diag) stage_panel(srcJ, PJ[0], nJu, t, 0);
    __syncthreads();

    for (int kc = 0; kc < DIM / KC; kc++) {   // 32 chunks
        int cur = kc & 1;
        if (kc + 1 < DIM / KC) {
            stage_panel(srcI, PI[cur ^ 1], 1024, t, (kc + 1) * KC);
            if (!diag) stage_panel(srcJ, PJ[cur ^ 1], nJu, t, (kc + 1) * KC);
        }
        const short* PA = PI[cur];
        const short* PB = diag ? PI[cur] : PJ[cur];
#pragma unroll
        for (int kk = 0; kk < 2; kk++) {
            int kb = kk * 32 + (lane >> 4) * 8;
            int ra = rw * 32 + (lane & 15);
            bf16x8 a0 = *(const bf16x8*)&PA[ra * KC + (kb ^ ((ra & 7) << 3))];
            int ra1 = ra + 16;
            bf16x8 a1 = *(const bf16x8*)&PA[ra1 * KC + (kb ^ ((ra1 & 7) << 3))];
#pragma unroll
            for (int f = 0; f < 4; f++) {
                if (f < NCF) {
                    int rb = colbase + f * 16 + (lane & 15);
                    bf16x8 bb = *(const bf16x8*)&PB[rb * KC + (kb ^ ((rb & 7) << 3))];
                    acc[0][f] = __builtin_amdgcn_mfma_f32_16x16x32_bf16(a0, bb, acc[0][f], 0, 0, 0);
                    acc[1][f] = __builtin_amdgcn_mfma_f32_16x16x32_bf16(a1, bb, acc[1][f], 0, 0, 0);
                }
            }
        }
        __syncthreads();
    }

    if (!isD) {
        size_t gbase = (size_t)j * (512 * 512);
#pragma unroll
        for (int rf = 0; rf < 2; rf++)
#pragma unroll
            for (int f = 0; f < 4; f++)
#pragma unroll
                for (int r = 0; r < 4; r++) {
                    int lrow = I * 128 + rw * 32 + rf * 16 + (lane >> 4) * 4 + r;
                    int lcol = J * 128 + colbase + f * 16 + (lane & 15);
                    unsigned short hv = f2bf(acc[rf][f][r]);
                    Gbf[gbase + (size_t)lrow * 512 + lcol] = hv;
                    if (I != J)  // materialize symmetry for full-row reads
                        Gbf[gbase + (size_t)lcol * 512 + lrow] = hv;
                }
    } else {
#pragma unroll
        for (int rf = 0; rf < 2; rf++)
#pragma unroll
            for (int f = 0; f < 2; f++)
#pragma unroll
                for (int r = 0; r < 4; r++) {
                    int grow = start + I * 128 + rw * 32 + rf * 16 + (lane >> 4) * 4 + r;
                    int gcol = colbase + f * 16 + (lane & 15);
                    D0[(size_t)grow * KCLS + gcol] = acc[rf][f][r];
                }
    }
}

// ---------------------------------------------------------------------------
// Kernel 6 (v2): parallel coalesced finalize. Block = (class-group g, range j),
// 512 threads = 8 waves, wave w owns class c = g*8+w.
// Phase 2: wave-parallel ordered event list (shfl prefix scan).
// Phase 3: for each event e of c, ALL lanes read Gram row G[e][:] (full row now
//   materialized, contiguous, coalesced) accumulating corr(t,c) masked t>e; the
//   thread whose token IS event e_j ends holding rdv_j = d0 + sum_{i<j} G[e_i][e_j].
// Phase 4: 8-scalar n2 stage scan per class -> invna stages.
// Phase 5: fully parallel output.
__global__ __launch_bounds__(512) void finalize_kernel(
    const int* __restrict__ lab, const float* __restrict__ D0,
    const unsigned short* __restrict__ Gbf, const float* __restrict__ vnorm2,
    const float* __restrict__ n2snap, const int* __restrict__ cnt_before,
    float* __restrict__ out) {
    __shared__ unsigned char lbl[RANGE];
    __shared__ short evl[RANGE];
    __shared__ short evcnt_s[8];
    __shared__ short evoff_s[9];
    __shared__ float corrb[8][RANGE];   // 16 KB
    __shared__ float cntb[8][RANGE];    // 16 KB
    __shared__ float rdv[RANGE];
    __shared__ float invna[RANGE + 8];
    __shared__ unsigned char vgs[8];

    int bid = blockIdx.x;
    int g = bid >> 5, jr = bid & 31;
    int g8 = g * 8;
    int start = jr * RANGE;
    int t = threadIdx.x, lane = t & 63, w = t >> 6;
    int c = g8 + w;

    lbl[t] = (unsigned char)lab[start + t];
    if (t < 8) vgs[t] = (cnt_before[jr * KCLS + g8 + t] == 0) ? 1 : 0;
    __syncthreads();

    // phase 2: per-wave ordered event list for class c
    unsigned char myl[8];
    int cntL = 0;
#pragma unroll
    for (int i = 0; i < 8; i++) {
        myl[i] = lbl[lane * 8 + i];
        cntL += (myl[i] == c) ? 1 : 0;
    }
    int pre = cntL;
    for (int s = 1; s < 64; s <<= 1) {
        int v = __shfl_up(pre, s, 64);
        if (lane >= s) pre += v;
    }
    int tot = __shfl(pre, 63, 64);
    if (lane == 63) evcnt_s[w] = (short)tot;
    __syncthreads();
    if (t == 0) {
        int s = 0;
        for (int i = 0; i < 8; i++) { evoff_s[i] = (short)s; s += evcnt_s[i]; }
        evoff_s[8] = (short)s;
    }
    __syncthreads();
    int off = evoff_s[w], m = evcnt_s[w];
    {
        int wr = off + (pre - cntL);
#pragma unroll
        for (int i = 0; i < 8; i++)
            if (myl[i] == c) evl[wr++] = (short)(lane * 8 + i);
    }
    __syncthreads();

    // phase 3: coalesced Gram-row broadcast accumulation
    const unsigned short* grb = Gbf + (size_t)jr * 262144;
    int vg = vgs[w];
#pragma unroll 1
    for (int chk = 0; chk < 8; chk++) {
        int tk = chk * 64 + lane;
        float corr = 0.f;
        int cnt = 0;
#pragma unroll 1
        for (int i = 0; i < m; i++) {
            int e = evl[off + i];
            float gv = bf2f(grb[(size_t)e * 512 + tk]);
            bool after = (tk > e);
            corr += after ? gv : 0.f;
            cnt += after ? 1 : 0;
        }
        corrb[w][tk] = corr;
        cntb[w][tk] = (float)cnt;
        if ((int)lbl[tk] == c) {
            float d0v = vg ? 0.f : D0[(size_t)(start + tk) * KCLS + c];
            rdv[off + cnt] = d0v + corr;
        }
    }
    __syncthreads();

    // phase 4: n2 stage scan (8 scalar iterations per class)
    if (t < 8) {
        int o = evoff_s[t], mm = evcnt_s[t];
        int vgt = vgs[t];
        float n2 = n2snap[jr * KCLS + g8 + t];
        invna[o + t] = 1.0f / fmaxf(sqrtf(n2), EPS);
        for (int i = 1; i <= mm; i++) {
            int e = evl[o + i - 1];
            float xn2 = vnorm2[start + e];
            if (vgt && i == 1) n2 = xn2;
            else n2 += 2.f * rdv[o + i - 1] + xn2;
            invna[o + t + i] = 1.0f / fmaxf(sqrtf(n2), EPS);
        }
    }
    __syncthreads();

    // phase 5: parallel output, thread t = token t
    {
        float4 d0a = *(const float4*)&D0[(size_t)(start + t) * KCLS + g8];
        float4 d0b = *(const float4*)&D0[(size_t)(start + t) * KCLS + g8 + 4];
        float d0[8] = {d0a.x, d0a.y, d0a.z, d0a.w, d0b.x, d0b.y, d0b.z, d0b.w};
        float nvinv = 1.0f / fmaxf(sqrtf(vnorm2[start + t]), EPS);
        float o8[8];
#pragma unroll
        for (int cc = 0; cc < 8; cc++) {
            float corr = corrb[cc][t];
            int cnt = (int)cntb[cc][t];
            float dot = (vgs[cc] && cnt > 0) ? corr : (d0[cc] + corr);
            o8[cc] = dot * invna[evoff_s[cc] + cc + cnt] * nvinv;
        }
        float4 oa = {o8[0], o8[1], o8[2], o8[3]};
        float4 ob = {o8[4], o8[5], o8[6], o8[7]};
        float* op = &out[(size_t)(start + t) * KCLS + g8];
        *(float4*)op = oa;
        *(float4*)(op + 4) = ob;
    }
}

// ---------------------------------------------------------------------------
extern "C" void kernel_launch(void* const* d_in, const int* in_sizes, int n_in,
                              void* d_out, int out_size, void* d_ws, size_t ws_size,
                              hipStream_t stream) {
    const float* inputs = (const float*)d_in[0];
    const float* class_avgs = (const float*)d_in[1];
    const int* labels_raw = (const int*)d_in[2];
    float* out = (float*)d_out;
    char* ws = (char*)d_ws;

    size_t off = 0;
    int* lab = (int*)(ws + off);          off += (size_t)N_TOK * 4;
    int* cnt_range = (int*)(ws + off);    off += (size_t)JRANGES * KCLS * 4;
    int* cnt_before = (int*)(ws + off);   off += (size_t)JRANGES * KCLS * 4;
    float* n2snap = (float*)(ws + off);   off += (size_t)JRANGES * KCLS * 4;
    float* vnorm2 = (float*)(ws + off);   off += (size_t)N_TOK * 4;
    off = (off + 255) & ~(size_t)255;
    unsigned short* Xb = (unsigned short*)(ws + off);
    off += (size_t)N_TOK * DIM * 2;                                   // 64 MB
    unsigned short* Sb = (unsigned short*)(ws + off);
    off += (size_t)JRANGES * KCLS * DIM * 2;                          // 8 MB
    float* D0 = (float*)(ws + off);       off += (size_t)N_TOK * KCLS * 4;  // 4 MB
    float* spart = (float*)(ws + off);    // 16 MB, dead after snapnorm
    unsigned short* Gbf = (unsigned short*)spart;  // overlay (16 MB)

    fix_labels_kernel<<<N_TOK / 256, 256, 0, stream>>>(labels_raw, lab);
    prep_kernel<<<N_TOK / 4, 256, 0, stream>>>(inputs, Xb, vnorm2);
    partials_kernel<<<JRANGES * KCLS, 256, 0, stream>>>(Xb, lab, spart, cnt_range);
    scan_kernel<<<(KCLS * (DIM / 4)) / 256, 256, 0, stream>>>(class_avgs, spart, Sb,
                                                              cnt_range, cnt_before);
    snapnorm_kernel<<<JRANGES * KCLS, 64, 0, stream>>>(spart, n2snap);
    gemm_kernel<<<14 * JRANGES, 512, 0, stream>>>(Xb, Sb, D0, Gbf);
    finalize_kernel<<<8 * JRANGES, 512, 0, stream>>>(lab, D0, Gbf, vnorm2, n2snap,
                                                     cnt_before, out);
}

// Round 11
// 179.512 us; speedup vs baseline: 2.0197x; 1.0387x over previous
//
#include <hip/hip_runtime.h>
#include <hip/hip_bf16.h>

#define N_TOK 16384
#define DIM 2048
#define KCLS 64
#define JRANGES 32
#define RANGE 512   // N_TOK / JRANGES
#define KC 64       // GEMM K-chunk (bf16, double-buffered)
#define EPS 1e-8f

typedef short bf16x8 __attribute__((ext_vector_type(8)));
typedef unsigned short u16x8 __attribute__((ext_vector_type(8)));
typedef float f32x4 __attribute__((ext_vector_type(4)));

__device__ __forceinline__ unsigned short f2bf(float f) {
    unsigned u = __float_as_uint(f);
    u += 0x7fffu + ((u >> 16) & 1u);
    return (unsigned short)(u >> 16);
}
__device__ __forceinline__ float bf2f(unsigned short s) {
    return __uint_as_float(((unsigned)s) << 16);
}

__device__ __forceinline__ float dpp_sum64(float x) {
    x += __int_as_float(__builtin_amdgcn_update_dpp(0, __float_as_int(x), 0x111, 0xf, 0xf, true));
    x += __int_as_float(__builtin_amdgcn_update_dpp(0, __float_as_int(x), 0x112, 0xf, 0xf, true));
    x += __int_as_float(__builtin_amdgcn_update_dpp(0, __float_as_int(x), 0x114, 0xf, 0xf, true));
    x += __int_as_float(__builtin_amdgcn_update_dpp(0, __float_as_int(x), 0x118, 0xf, 0xf, true));
    x += __int_as_float(__builtin_amdgcn_update_dpp(0, __float_as_int(x), 0x142, 0xf, 0xf, true));
    x += __int_as_float(__builtin_amdgcn_update_dpp(0, __float_as_int(x), 0x143, 0xf, 0xf, true));
    return x;  // valid in lane 63 only
}

// ---------------------------------------------------------------------------
// Kernel 1: prep — cast X to bf16 + exact fp32 token norms.
// Fused extras: blocks 0..63 normalize the labels chunk (int64/int32 sniff);
// blocks 64..71 zero n2snap (scan accumulates into it atomically).
__global__ __launch_bounds__(256) void prep_kernel(
    const float* __restrict__ x, unsigned short* __restrict__ xb,
    float* __restrict__ vnorm2, const int* __restrict__ raw,
    int* __restrict__ lab, float* __restrict__ n2snap) {
    int bid = blockIdx.x, tid = threadIdx.x;
    if (bid < 64) {  // label duty (block-uniform branch)
        __shared__ int not64;
        if (tid == 0) not64 = 0;
        __syncthreads();
        int n0 = bid * 256 + tid;
        int lo = raw[2 * n0], hi = raw[2 * n0 + 1];
        if (hi != 0 || lo < 0 || lo >= KCLS) atomicOr(&not64, 1);
        __syncthreads();
        lab[n0] = not64 ? raw[n0] : raw[2 * n0];
    } else if (bid < 72) {
        n2snap[(bid - 64) * 256 + tid] = 0.f;
    }
    int w4 = tid >> 6, lane = tid & 63;
    int n = bid * 4 + w4;
    const float* v = x + (size_t)n * DIM;
    unsigned short* o = xb + (size_t)n * DIM;
    float p = 0.f;
#pragma unroll
    for (int it = 0; it < 8; it++) {
        float4 a = *(const float4*)(v + it * 256 + lane * 4);
        p = fmaf(a.x, a.x, p); p = fmaf(a.y, a.y, p);
        p = fmaf(a.z, a.z, p); p = fmaf(a.w, a.w, p);
        ushort4 h = make_ushort4(f2bf(a.x), f2bf(a.y), f2bf(a.z), f2bf(a.w));
        *(ushort4*)(o + it * 256 + lane * 4) = h;
    }
    p = dpp_sum64(p);
    if (lane == 63) vnorm2[n] = p;
}

// ---------------------------------------------------------------------------
// Kernel 2: per-(range, class) partial sum of class-k token vectors (bf16 in,
// fp32 accum). bid = k*32 + j -> bid%8 == j%8 (XCD locality).
__global__ __launch_bounds__(256) void partials_kernel(
    const unsigned short* __restrict__ xb, const int* __restrict__ lab,
    float* __restrict__ spart, int* __restrict__ cnt_range) {
    int bid = blockIdx.x;
    int j = bid & 31, k = bid >> 5;
    int t = threadIdx.x;
    __shared__ int ll[RANGE];
    __shared__ short ml[RANGE];
    __shared__ int nm_s;
    for (int i = t; i < RANGE; i += 256) ll[i] = lab[j * RANGE + i];
    __syncthreads();
    if (t == 0) {
        int nm = 0;
        for (int i = 0; i < RANGE; i++)
            if (ll[i] == k) ml[nm++] = (short)i;
        nm_s = nm;
        cnt_range[j * KCLS + k] = nm;
    }
    __syncthreads();
    int nm = nm_s;
    float acc[8] = {0, 0, 0, 0, 0, 0, 0, 0};
    for (int m = 0; m < nm; m++) {
        const unsigned short* r = xb + (size_t)(j * RANGE + (int)ml[m]) * DIM + t * 8;
        u16x8 hv = *(const u16x8*)r;
#pragma unroll
        for (int i = 0; i < 8; i++) acc[i] += bf2f(hv[i]);
    }
    float* dst = spart + ((size_t)j * KCLS + k) * DIM + t * 8;
    *(float4*)dst = make_float4(acc[0], acc[1], acc[2], acc[3]);
    *(float4*)(dst + 4) = make_float4(acc[4], acc[5], acc[6], acc[7]);
}

// ---------------------------------------------------------------------------
// Kernel 3: in-place exclusive scan over ranges -> boundary snapshots;
// emits bf16 mirror Sb AND accumulates ||snapshot||^2 into n2snap
// (per-wave DPP reduce + one atomicAdd per wave; snapnorm kernel deleted).
__global__ __launch_bounds__(256) void scan_kernel(
    const float* __restrict__ avgs, float* __restrict__ spart,
    unsigned short* __restrict__ Sb, float* __restrict__ n2snap,
    const int* __restrict__ cnt_range, int* __restrict__ cnt_before) {
    int t = blockIdx.x * 256 + threadIdx.x;  // 32768 threads
    int lane = threadIdx.x & 63;
    int k = t >> 9;
    int d4 = t & 511;
    int d = d4 * 4;
    float4 run = {0, 0, 0, 0};
    int cb = 0;
    float4 init = *(const float4*)(avgs + (size_t)k * DIM + d);
    for (int j = 0; j < JRANGES; j++) {
        size_t idx = ((size_t)j * KCLS + k) * DIM + d;
        float4 part = *(const float4*)(spart + idx);
        float4 w = (cb == 0) ? init : run;
        *(float4*)(spart + idx) = w;
        *(ushort4*)(Sb + idx) = make_ushort4(f2bf(w.x), f2bf(w.y), f2bf(w.z), f2bf(w.w));
        float s = 0.f;
        s = fmaf(w.x, w.x, s); s = fmaf(w.y, w.y, s);
        s = fmaf(w.z, w.z, s); s = fmaf(w.w, w.w, s);
        s = dpp_sum64(s);
        if (lane == 63) atomicAdd(&n2snap[j * KCLS + k], s);
        if (d4 == 0) cnt_before[j * KCLS + k] = cb;
        run.x += part.x; run.y += part.y; run.z += part.z; run.w += part.w;
        cb += cnt_range[j * KCLS + k];
    }
}

// ---------------------------------------------------------------------------
// stage one bf16 panel K-chunk into LDS via global_load_lds (m173 pattern:
// linear LDS dest, XOR swizzle applied to the GLOBAL source address).
__device__ __forceinline__ void stage_panel(
    const unsigned short* __restrict__ src, short* dst, int nunits,
    int t, int kcoff) {
#pragma unroll
    for (int i = 0; i < 2; i++) {
        int u = t + 512 * i;
        if (u < nunits) {
            int row = u >> 3, gsw = u & 7;
            int g = gsw ^ (row & 7);
            const unsigned short* s = src + (size_t)row * DIM + kcoff + g * 8;
            __builtin_amdgcn_global_load_lds(
                (__attribute__((address_space(1))) void*)s,
                (__attribute__((address_space(3))) void*)(dst + u * 8),
                16, 0, 0);
        }
    }
}

// ---------------------------------------------------------------------------
// Kernel 4: per-range GEMMs via bf16 MFMA, double-buffered global_load_lds
// staging (KC=64). tt 0..9: G-tiles (I>=J, 128x128) of G = X·X^T;
// tt 10..13: D-tiles (128 tokens x 64 classes) of D0 = X·S^T.
// Off-diag G tiles: direct store + transposed store via LDS transpose (reuse
// PI as 128x128 bf16 buffer; XOR-swizzled write AND read -> coalesced 16B
// global stores; replaces round-10's 2-byte scattered transposed stores).
__global__ __launch_bounds__(512, 4) void gemm_kernel(
    const unsigned short* __restrict__ xb, const unsigned short* __restrict__ Sb,
    float* __restrict__ D0, unsigned short* __restrict__ Gbf) {
    __shared__ short PI[2][128 * KC];   // 2 x 16 KB (also reused as 128x128 TT)
    __shared__ short PJ[2][128 * KC];   // 2 x 16 KB
    static const char TIa[14] = {0,1,1,2,2,2,3,3,3,3, 0,1,2,3};
    static const char TJa[14] = {0,0,1,0,1,2,0,1,2,3, 0,0,0,0};

    int bid = blockIdx.x;
    int j = bid & 31;
    int tt = bid >> 5;
    int I = TIa[tt], J = TJa[tt];
    bool isD = (tt >= 10);
    bool diag = (!isD) && (I == J);
    int start = j * RANGE;
    int t = threadIdx.x, lane = t & 63, w = t >> 6;
    int rw = w & 3, cw = w >> 2;
    int NCF = isD ? 2 : 4;
    int colbase = isD ? cw * 32 : cw * 64;

    f32x4 acc[2][4];
#pragma unroll
    for (int a = 0; a < 2; a++)
#pragma unroll
        for (int b = 0; b < 4; b++) acc[a][b] = (f32x4){0.f, 0.f, 0.f, 0.f};

    const unsigned short* srcI = xb + (size_t)(start + I * 128) * DIM;
    const unsigned short* srcJ = isD ? (Sb + (size_t)(j * KCLS) * DIM)
                                     : (xb + (size_t)(start + J * 128) * DIM);
    int nJu = isD ? 512 : 1024;

    stage_panel(srcI, PI[0], 1024, t, 0);
    if (!diag) stage_panel(srcJ, PJ[0], nJu, t, 0);
    __syncthreads();

    for (int kc = 0; kc < DIM / KC; kc++) {   // 32 chunks
        int cur = kc & 1;
        if (kc + 1 < DIM / KC) {
            stage_panel(srcI, PI[cur ^ 1], 1024, t, (kc + 1) * KC);
            if (!diag) stage_panel(srcJ, PJ[cur ^ 1], nJu, t, (kc + 1) * KC);
        }
        const short* PA = PI[cur];
        const short* PB = diag ? PI[cur] : PJ[cur];
#pragma unroll
        for (int kk = 0; kk < 2; kk++) {
            int kb = kk * 32 + (lane >> 4) * 8;
            int ra = rw * 32 + (lane & 15);
            bf16x8 a0 = *(const bf16x8*)&PA[ra * KC + (kb ^ ((ra & 7) << 3))];
            int ra1 = ra + 16;
            bf16x8 a1 = *(const bf16x8*)&PA[ra1 * KC + (kb ^ ((ra1 & 7) << 3))];
#pragma unroll
            for (int f = 0; f < 4; f++) {
                if (f < NCF) {
                    int rb = colbase + f * 16 + (lane & 15);
                    bf16x8 bb = *(const bf16x8*)&PB[rb * KC + (kb ^ ((rb & 7) << 3))];
                    acc[0][f] = __builtin_amdgcn_mfma_f32_16x16x32_bf16(a0, bb, acc[0][f], 0, 0, 0);
                    acc[1][f] = __builtin_amdgcn_mfma_f32_16x16x32_bf16(a1, bb, acc[1][f], 0, 0, 0);
                }
            }
        }
        __syncthreads();
    }

    if (!isD) {
        size_t gbase = (size_t)j * (512 * 512);
        short* TT = &PI[0][0];  // 128x128 bf16 transpose buffer (32 KB)
#pragma unroll
        for (int rf = 0; rf < 2; rf++)
#pragma unroll
            for (int f = 0; f < 4; f++)
#pragma unroll
                for (int r = 0; r < 4; r++) {
                    int lr = rw * 32 + rf * 16 + (lane >> 4) * 4 + r;
                    int lc = colbase + f * 16 + (lane & 15);
                    unsigned short hv = f2bf(acc[rf][f][r]);
                    Gbf[gbase + (size_t)(I * 128 + lr) * 512 + J * 128 + lc] = hv;
                    if (I != J)  // swizzled LDS write for the transpose
                        TT[lc * 128 + (lr ^ ((lc & 15) << 3))] = (short)hv;
                }
        if (I != J) {
            __syncthreads();
#pragma unroll
            for (int i = 0; i < 4; i++) {  // coalesced transposed store
                int u = t + 512 * i;       // 2048 chunks of 8 bf16
                int tr = u >> 4, tc = u & 15;
                u16x8 v = *(const u16x8*)&TT[tr * 128 + ((tc * 8) ^ ((tr & 15) << 3))];
                *(u16x8*)&Gbf[gbase + (size_t)(J * 128 + tr) * 512 + I * 128 + tc * 8] = v;
            }
        }
    } else {
#pragma unroll
        for (int rf = 0; rf < 2; rf++)
#pragma unroll
            for (int f = 0; f < 2; f++)
#pragma unroll
                for (int r = 0; r < 4; r++) {
                    int grow = start + I * 128 + rw * 32 + rf * 16 + (lane >> 4) * 4 + r;
                    int gcol = colbase + f * 16 + (lane & 15);
                    D0[(size_t)grow * KCLS + gcol] = acc[rf][f][r];
                }
    }
}

// ---------------------------------------------------------------------------
// Kernel 5: parallel coalesced finalize (unchanged from round 10).
__global__ __launch_bounds__(512) void finalize_kernel(
    const int* __restrict__ lab, const float* __restrict__ D0,
    const unsigned short* __restrict__ Gbf, const float* __restrict__ vnorm2,
    const float* __restrict__ n2snap, const int* __restrict__ cnt_before,
    float* __restrict__ out) {
    __shared__ unsigned char lbl[RANGE];
    __shared__ short evl[RANGE];
    __shared__ short evcnt_s[8];
    __shared__ short evoff_s[9];
    __shared__ float corrb[8][RANGE];   // 16 KB
    __shared__ float cntb[8][RANGE];    // 16 KB
    __shared__ float rdv[RANGE];
    __shared__ float invna[RANGE + 8];
    __shared__ unsigned char vgs[8];

    int bid = blockIdx.x;
    int g = bid >> 5, jr = bid & 31;
    int g8 = g * 8;
    int start = jr * RANGE;
    int t = threadIdx.x, lane = t & 63, w = t >> 6;
    int c = g8 + w;

    lbl[t] = (unsigned char)lab[start + t];
    if (t < 8) vgs[t] = (cnt_before[jr * KCLS + g8 + t] == 0) ? 1 : 0;
    __syncthreads();

    // per-wave ordered event list for class c
    unsigned char myl[8];
    int cntL = 0;
#pragma unroll
    for (int i = 0; i < 8; i++) {
        myl[i] = lbl[lane * 8 + i];
        cntL += (myl[i] == c) ? 1 : 0;
    }
    int pre = cntL;
    for (int s = 1; s < 64; s <<= 1) {
        int v = __shfl_up(pre, s, 64);
        if (lane >= s) pre += v;
    }
    int tot = __shfl(pre, 63, 64);
    if (lane == 63) evcnt_s[w] = (short)tot;
    __syncthreads();
    if (t == 0) {
        int s = 0;
        for (int i = 0; i < 8; i++) { evoff_s[i] = (short)s; s += evcnt_s[i]; }
        evoff_s[8] = (short)s;
    }
    __syncthreads();
    int off = evoff_s[w], m = evcnt_s[w];
    {
        int wr = off + (pre - cntL);
#pragma unroll
        for (int i = 0; i < 8; i++)
            if (myl[i] == c) evl[wr++] = (short)(lane * 8 + i);
    }
    __syncthreads();

    // coalesced Gram-row broadcast accumulation
    const unsigned short* grb = Gbf + (size_t)jr * 262144;
    int vg = vgs[w];
#pragma unroll 1
    for (int chk = 0; chk < 8; chk++) {
        int tk = chk * 64 + lane;
        float corr = 0.f;
        int cnt = 0;
#pragma unroll 1
        for (int i = 0; i < m; i++) {
            int e = evl[off + i];
            float gv = bf2f(grb[(size_t)e * 512 + tk]);
            bool after = (tk > e);
            corr += after ? gv : 0.f;
            cnt += after ? 1 : 0;
        }
        corrb[w][tk] = corr;
        cntb[w][tk] = (float)cnt;
        if ((int)lbl[tk] == c) {
            float d0v = vg ? 0.f : D0[(size_t)(start + tk) * KCLS + c];
            rdv[off + cnt] = d0v + corr;
        }
    }
    __syncthreads();

    // n2 stage scan (8 scalar iterations per class)
    if (t < 8) {
        int o = evoff_s[t], mm = evcnt_s[t];
        int vgt = vgs[t];
        float n2 = n2snap[jr * KCLS + g8 + t];
        invna[o + t] = 1.0f / fmaxf(sqrtf(n2), EPS);
        for (int i = 1; i <= mm; i++) {
            int e = evl[o + i - 1];
            float xn2 = vnorm2[start + e];
            if (vgt && i == 1) n2 = xn2;
            else n2 += 2.f * rdv[o + i - 1] + xn2;
            invna[o + t + i] = 1.0f / fmaxf(sqrtf(n2), EPS);
        }
    }
    __syncthreads();

    // parallel output, thread t = token t
    {
        float4 d0a = *(const float4*)&D0[(size_t)(start + t) * KCLS + g8];
        float4 d0b = *(const float4*)&D0[(size_t)(start + t) * KCLS + g8 + 4];
        float d0[8] = {d0a.x, d0a.y, d0a.z, d0a.w, d0b.x, d0b.y, d0b.z, d0b.w};
        float nvinv = 1.0f / fmaxf(sqrtf(vnorm2[start + t]), EPS);
        float o8[8];
#pragma unroll
        for (int cc = 0; cc < 8; cc++) {
            float corr = corrb[cc][t];
            int cnt = (int)cntb[cc][t];
            float dot = (vgs[cc] && cnt > 0) ? corr : (d0[cc] + corr);
            o8[cc] = dot * invna[evoff_s[cc] + cc + cnt] * nvinv;
        }
        float4 oa = {o8[0], o8[1], o8[2], o8[3]};
        float4 ob = {o8[4], o8[5], o8[6], o8[7]};
        float* op = &out[(size_t)(start + t) * KCLS + g8];
        *(float4*)op = oa;
        *(float4*)(op + 4) = ob;
    }
}

// ---------------------------------------------------------------------------
extern "C" void kernel_launch(void* const* d_in, const int* in_sizes, int n_in,
                              void* d_out, int out_size, void* d_ws, size_t ws_size,
                              hipStream_t stream) {
    const float* inputs = (const float*)d_in[0];
    const float* class_avgs = (const float*)d_in[1];
    const int* labels_raw = (const int*)d_in[2];
    float* out = (float*)d_out;
    char* ws = (char*)d_ws;

    size_t off = 0;
    int* lab = (int*)(ws + off);          off += (size_t)N_TOK * 4;
    int* cnt_range = (int*)(ws + off);    off += (size_t)JRANGES * KCLS * 4;
    int* cnt_before = (int*)(ws + off);   off += (size_t)JRANGES * KCLS * 4;
    float* n2snap = (float*)(ws + off);   off += (size_t)JRANGES * KCLS * 4;
    float* vnorm2 = (float*)(ws + off);   off += (size_t)N_TOK * 4;
    off = (off + 255) & ~(size_t)255;
    unsigned short* Xb = (unsigned short*)(ws + off);
    off += (size_t)N_TOK * DIM * 2;                                   // 64 MB
    unsigned short* Sb = (unsigned short*)(ws + off);
    off += (size_t)JRANGES * KCLS * DIM * 2;                          // 8 MB
    float* D0 = (float*)(ws + off);       off += (size_t)N_TOK * KCLS * 4;  // 4 MB
    float* spart = (float*)(ws + off);    // 16 MB, dead after scan
    unsigned short* Gbf = (unsigned short*)spart;  // overlay (16 MB)

    prep_kernel<<<N_TOK / 4, 256, 0, stream>>>(inputs, Xb, vnorm2, labels_raw,
                                               lab, n2snap);
    partials_kernel<<<JRANGES * KCLS, 256, 0, stream>>>(Xb, lab, spart, cnt_range);
    scan_kernel<<<(KCLS * (DIM / 4)) / 256, 256, 0, stream>>>(class_avgs, spart, Sb,
                                                              n2snap, cnt_range,
                                                              cnt_before);
    gemm_kernel<<<14 * JRANGES, 512, 0, stream>>>(Xb, Sb, D0, Gbf);
    finalize_kernel<<<8 * JRANGES, 512, 0, stream>>>(lab, D0, Gbf, vnorm2, n2snap,
                                                     cnt_before, out);
}